// Round 1
// baseline (943.656 us; speedup 1.0000x reference)
//
#include <hip/hip_runtime.h>
#include <math.h>

// GraphSAGE 2-layer + MLP head + softmax(2)
// x[N,48] f32, edge_index[2,E] int32, weights f32, out[N,2] f32.

__global__ __launch_bounds__(256) void edge_agg1(
    const float* __restrict__ x, const int* __restrict__ ei,
    float* __restrict__ agg, float* __restrict__ cnt, int E) {
  long long t = (long long)blockIdx.x * blockDim.x + threadIdx.x;
  int e = (int)(t >> 6);
  int f = (int)(t & 63);
  if (e >= E) return;
  int s = ei[e];
  int d = ei[E + e];
  if (f < 48) {
    atomicAdd(&agg[(long long)d * 48 + f], x[(long long)s * 48 + f]);
  }
  if (f == 0) {
    atomicAdd(&cnt[d], 1.0f);
  }
}

__global__ __launch_bounds__(256) void edge_agg2(
    const float* __restrict__ h, const int* __restrict__ ei,
    float* __restrict__ agg, int E) {
  long long t = (long long)blockIdx.x * blockDim.x + threadIdx.x;
  int e = (int)(t >> 6);
  int f = (int)(t & 63);
  if (e >= E) return;
  int s = ei[e];
  int d = ei[E + e];
  atomicAdd(&agg[(long long)d * 64 + f], h[(long long)s * 64 + f]);
}

// h1 = sigmoid(mean1 @ W1l + b1l + x @ W1r)
__global__ __launch_bounds__(256) void node1(
    const float* __restrict__ x, const float* __restrict__ agg,
    const float* __restrict__ cnt,
    const float* __restrict__ W1l, const float* __restrict__ b1l,
    const float* __restrict__ W1r,
    float* __restrict__ h1, int n_nodes) {
  __shared__ float sWl[48 * 64];
  __shared__ float sWr[48 * 64];
  __shared__ float sb[64];
  for (int i = threadIdx.x; i < 48 * 64; i += 256) {
    sWl[i] = W1l[i];
    sWr[i] = W1r[i];
  }
  if (threadIdx.x < 64) sb[threadIdx.x] = b1l[threadIdx.x];
  __syncthreads();
  int n = blockIdx.x * 256 + threadIdx.x;
  if (n >= n_nodes) return;
  float xr[48], mr[48];
  float inv = 1.0f / fmaxf(cnt[n], 1.0f);
  const float* xp = x + (long long)n * 48;
  const float* ap = agg + (long long)n * 48;
#pragma unroll
  for (int k = 0; k < 48; k++) {
    xr[k] = xp[k];
    mr[k] = ap[k] * inv;
  }
  float* hp = h1 + (long long)n * 64;
  for (int j = 0; j < 64; j++) {
    float acc = sb[j];
#pragma unroll
    for (int k = 0; k < 48; k++) {
      acc += mr[k] * sWl[k * 64 + j] + xr[k] * sWr[k * 64 + j];
    }
    hp[j] = 1.0f / (1.0f + __expf(-acc));
  }
}

// h2 = sigmoid(mean2 @ W2l + b2l + h1 @ W2r)
// h3 = sigmoid(h2 @ Wlin1 + blin1)
// out = softmax(h3 @ Wlin2 + blin2)
__global__ __launch_bounds__(256) void node2(
    const float* __restrict__ h1, const float* __restrict__ agg,
    const float* __restrict__ cnt,
    const float* __restrict__ W2l, const float* __restrict__ b2l,
    const float* __restrict__ W2r,
    const float* __restrict__ Wlin1, const float* __restrict__ blin1,
    const float* __restrict__ Wlin2, const float* __restrict__ blin2,
    float* __restrict__ out, int n_nodes) {
  __shared__ float sW2l[64 * 64];
  __shared__ float sW2r[64 * 64];
  __shared__ float sWl1[64 * 64];
  __shared__ float sb2[64], sbl1[64], sWl2[128], sbl2[2];
  for (int i = threadIdx.x; i < 64 * 64; i += 256) {
    sW2l[i] = W2l[i];
    sW2r[i] = W2r[i];
    sWl1[i] = Wlin1[i];
  }
  if (threadIdx.x < 128) sWl2[threadIdx.x] = Wlin2[threadIdx.x];
  if (threadIdx.x < 64) {
    sb2[threadIdx.x] = b2l[threadIdx.x];
    sbl1[threadIdx.x] = blin1[threadIdx.x];
  }
  if (threadIdx.x < 2) sbl2[threadIdx.x] = blin2[threadIdx.x];
  __syncthreads();
  int n = blockIdx.x * 256 + threadIdx.x;
  if (n >= n_nodes) return;
  float hr[64], mr[64];
  float inv = 1.0f / fmaxf(cnt[n], 1.0f);
  const float* hp = h1 + (long long)n * 64;
  const float* ap = agg + (long long)n * 64;
#pragma unroll
  for (int k = 0; k < 64; k++) {
    hr[k] = hp[k];
    mr[k] = ap[k] * inv;
  }
  float h2[64];
  for (int j = 0; j < 64; j++) {
    float acc = sb2[j];
#pragma unroll
    for (int k = 0; k < 64; k++) {
      acc += mr[k] * sW2l[k * 64 + j] + hr[k] * sW2r[k * 64 + j];
    }
    h2[j] = 1.0f / (1.0f + __expf(-acc));
  }
  float h3[64];
  for (int j = 0; j < 64; j++) {
    float acc = sbl1[j];
#pragma unroll
    for (int k = 0; k < 64; k++) {
      acc += h2[k] * sWl1[k * 64 + j];
    }
    h3[j] = 1.0f / (1.0f + __expf(-acc));
  }
  float l0 = sbl2[0], l1 = sbl2[1];
#pragma unroll
  for (int k = 0; k < 64; k++) {
    l0 += h3[k] * sWl2[k * 2 + 0];
    l1 += h3[k] * sWl2[k * 2 + 1];
  }
  float m = fmaxf(l0, l1);
  float p0 = __expf(l0 - m), p1 = __expf(l1 - m);
  float s = 1.0f / (p0 + p1);
  out[(long long)n * 2 + 0] = p0 * s;
  out[(long long)n * 2 + 1] = p1 * s;
}

extern "C" void kernel_launch(void* const* d_in, const int* in_sizes, int n_in,
                              void* d_out, int out_size, void* d_ws, size_t ws_size,
                              hipStream_t stream) {
  const float* x     = (const float*)d_in[0];
  const int*   ei    = (const int*)d_in[1];
  const float* W1l   = (const float*)d_in[2];
  const float* b1l   = (const float*)d_in[3];
  const float* W1r   = (const float*)d_in[4];
  const float* W2l   = (const float*)d_in[5];
  const float* b2l   = (const float*)d_in[6];
  const float* W2r   = (const float*)d_in[7];
  const float* Wlin1 = (const float*)d_in[8];
  const float* blin1 = (const float*)d_in[9];
  const float* Wlin2 = (const float*)d_in[10];
  const float* blin2 = (const float*)d_in[11];
  float* out = (float*)d_out;

  int n = in_sizes[0] / 48;
  int E = in_sizes[1] / 2;

  float* agg1 = (float*)d_ws;                       // [n,48]
  float* agg2 = agg1 + (size_t)n * 48;              // [n,64]
  float* cnt  = agg2 + (size_t)n * 64;              // [n]
  float* h1   = cnt + n;                            // [n,64]

  size_t zero_bytes = ((size_t)n * 48 + (size_t)n * 64 + (size_t)n) * sizeof(float);
  hipMemsetAsync(d_ws, 0, zero_bytes, stream);

  {
    long long tot = (long long)E * 64;
    int blocks = (int)((tot + 255) / 256);
    edge_agg1<<<blocks, 256, 0, stream>>>(x, ei, agg1, cnt, E);
  }
  node1<<<(n + 255) / 256, 256, 0, stream>>>(x, agg1, cnt, W1l, b1l, W1r, h1, n);
  {
    long long tot = (long long)E * 64;
    int blocks = (int)((tot + 255) / 256);
    edge_agg2<<<blocks, 256, 0, stream>>>(h1, ei, agg2, E);
  }
  node2<<<(n + 255) / 256, 256, 0, stream>>>(h1, agg2, cnt, W2l, b2l, W2r,
                                             Wlin1, blin1, Wlin2, blin2, out, n);
}